// Round 1
// baseline (201.003 us; speedup 1.0000x reference)
//
#include <hip/hip_runtime.h>
#include <hip/hip_bf16.h>

typedef __bf16 bf16x8_t __attribute__((ext_vector_type(8)));
typedef float f32x4_t __attribute__((ext_vector_type(4)));
using bf16 = __hip_bfloat16;

#define ASG __attribute__((address_space(1)))
#define ASL __attribute__((address_space(3)))

__device__ __forceinline__ void gld_lds16(const void* g, void* l) {
  // HW writes lane i of the wave at (wave-uniform lds base) + i*16 bytes.
  __builtin_amdgcn_global_load_lds((ASG void*)const_cast<void*>(g),
                                   (ASL void*)l, 16, 0, 0);
}

// 13 cubic B-spline basis values (grid 10, k=3, [-2,2]) + mish, written to LDS.
// Uniform knots: knots[j] = -3.2 + 0.4*j, j=0..16. For t=(x+3.2)/0.4 in cell
// c=floor(t), u=t-c, nonzero basis j=c-3..c with standard uniform cubic weights.
__device__ __forceinline__ void kan_feats_lds(bf16* dst, float x) {
#pragma unroll
  for (int j = 0; j < 13; ++j) dst[j] = __float2bfloat16(0.0f);
  float t = (x + 3.2f) * 2.5f;
  if (t >= 0.0f && t < 16.0f) {
    float tf = floorf(t);
    int c = (int)tf;
    float u = t - tf;
    float um = 1.0f - u;
    float u2 = u * u, u3 = u2 * u;
    const float s6 = 1.0f / 6.0f;
    float w0 = um * um * um * s6;
    float w1 = (3.0f * u3 - 6.0f * u2 + 4.0f) * s6;
    float w2 = (-3.0f * u3 + 3.0f * u2 + 3.0f * u + 1.0f) * s6;
    float w3 = u3 * s6;
    int j0 = c - 3;
    if (j0 >= 0)               dst[j0]     = __float2bfloat16(w0);
    if (j0 >= -1 && j0 <= 11)  dst[j0 + 1] = __float2bfloat16(w1);
    if (j0 >= -2 && j0 <= 10)  dst[j0 + 2] = __float2bfloat16(w2);
    if (j0 <= 9)               dst[j0 + 3] = __float2bfloat16(w3);
  }
  float sp = (x > 20.0f) ? x : log1pf(expf(x));
  dst[13] = __float2bfloat16(x * tanhf(sp));
}

// Wt[o][i*14+r] = r<13 ? coef[i][o][r]*sp[i][o] : sb[i][o]; zero-padded.
__global__ __launch_bounds__(256) void prep_w(
    const float* __restrict__ coef, const float* __restrict__ sb,
    const float* __restrict__ sp, bf16* __restrict__ Wt,
    int in, int out, int outPad, int Kpad) {
  const int idx = blockIdx.x * 256 + threadIdx.x;
  if (idx >= outPad * Kpad) return;
  const int o = idx / Kpad;
  const int kk = idx - o * Kpad;
  float v = 0.0f;
  if (o < out && kk < in * 14) {
    const int i = kk / 14;
    const int r = kk - i * 14;
    v = (r < 13) ? coef[((size_t)i * out + o) * 13 + r] * sp[(size_t)i * out + o]
                 : sb[(size_t)i * out + o];
  }
  Wt[(size_t)o * Kpad + kk] = __float2bfloat16(v);
}

// One block per image: 4x4 avg-pool 28x28 -> 49, then basis+mish -> A1 row (704 bf16).
__global__ __launch_bounds__(256) void pool_basis1(const float* __restrict__ x,
                                                   bf16* __restrict__ A1) {
  __shared__ __align__(16) float xs[784];
  __shared__ __align__(16) bf16 arow[704];
  const int b = blockIdx.x, t = threadIdx.x;
  if (t < 196) *(float4*)(&xs[t * 4]) = *(const float4*)(x + (size_t)b * 784 + t * 4);
  __syncthreads();
  if (t < 49) {
    const int oh = t / 7, ow = t % 7;
    float s = 0.f;
#pragma unroll
    for (int r = 0; r < 4; ++r)
#pragma unroll
      for (int c = 0; c < 4; ++c) s += xs[(oh * 4 + r) * 28 + ow * 4 + c];
    kan_feats_lds(&arow[t * 14], s * (1.0f / 16.0f));
  } else if (t < 67) {
    arow[686 + (t - 49)] = __float2bfloat16(0.0f);  // K pad 686..703
  }
  __syncthreads();
  if (t < 88) ((uint4*)((char*)A1 + (size_t)b * 1408))[t] = ((const uint4*)arow)[t];
}

// H (fp32, B x 256) -> augmented A (bf16, B x 3584), one block per row.
__global__ __launch_bounds__(256) void basis23(const float* __restrict__ Hin,
                                               bf16* __restrict__ Aout) {
  __shared__ __align__(16) bf16 arow[3584];
  const int b = blockIdx.x, t = threadIdx.x;
  kan_feats_lds(&arow[t * 14], Hin[(size_t)b * 256 + t]);
  __syncthreads();
  uint4* dst = (uint4*)((char*)Aout + (size_t)b * 7168);
  const uint4* src = (const uint4*)arow;
  dst[t] = src[t];
  if (t < 192) dst[256 + t] = src[256 + t];
}

// C[m][n] = sum_k A[m][k]*Wt[n][k] + bias[n]. 64x64 tile, N fixed 256 out stride.
__global__ __launch_bounds__(256) void gemm64(
    const bf16* __restrict__ A, const bf16* __restrict__ Wt,
    const float* __restrict__ bias, float* __restrict__ H, int K) {
  __shared__ __align__(16) bf16 As[64][32];
  __shared__ __align__(16) bf16 Bs[64][32];
  const int t = threadIdx.x;
  const int wv = t >> 6, lane = t & 63, quad = lane >> 4, lr = lane & 15;
  const int m0 = blockIdx.x * 64, n0 = blockIdx.y * 64;
  const int wm = (wv & 1) * 32, wn = (wv >> 1) * 32;
  const int srow = t >> 2, scol = (t & 3) * 8;
  const bf16* gA = A + (size_t)(m0 + srow) * K + scol;
  const bf16* gB = Wt + (size_t)(n0 + srow) * K + scol;
  void* ldsA = (char*)(&As[0][0]) + wv * 1024;
  void* ldsB = (char*)(&Bs[0][0]) + wv * 1024;
  f32x4_t acc00 = {0.f, 0.f, 0.f, 0.f}, acc01 = acc00, acc10 = acc00, acc11 = acc00;
  for (int k0 = 0; k0 < K; k0 += 32) {
    gld_lds16(gA + k0, ldsA);
    gld_lds16(gB + k0, ldsB);
    __syncthreads();
    bf16x8_t a0 = *(const bf16x8_t*)(&As[wm + lr][quad * 8]);
    bf16x8_t a1 = *(const bf16x8_t*)(&As[wm + 16 + lr][quad * 8]);
    bf16x8_t b0 = *(const bf16x8_t*)(&Bs[wn + lr][quad * 8]);
    bf16x8_t b1 = *(const bf16x8_t*)(&Bs[wn + 16 + lr][quad * 8]);
    acc00 = __builtin_amdgcn_mfma_f32_16x16x32_bf16(a0, b0, acc00, 0, 0, 0);
    acc01 = __builtin_amdgcn_mfma_f32_16x16x32_bf16(a0, b1, acc01, 0, 0, 0);
    acc10 = __builtin_amdgcn_mfma_f32_16x16x32_bf16(a1, b0, acc10, 0, 0, 0);
    acc11 = __builtin_amdgcn_mfma_f32_16x16x32_bf16(a1, b1, acc11, 0, 0, 0);
    __syncthreads();
  }
  const int cb = n0 + wn + lr;
  const float bn0 = bias[cb];
  const float bn1 = bias[cb + 16];
#pragma unroll
  for (int r = 0; r < 4; ++r) {
    const size_t r0 = (size_t)(m0 + wm + quad * 4 + r);
    H[r0 * 256 + cb] = acc00[r] + bn0;
    H[r0 * 256 + cb + 16] = acc01[r] + bn1;
    H[(r0 + 16) * 256 + cb] = acc10[r] + bn0;
    H[(r0 + 16) * 256 + cb + 16] = acc11[r] + bn1;
  }
}

// Layer-3 GEMM: N=16 (10 real), split-K over blockIdx.y (8 chunks of 448).
// partials layout [kc][n][m] so the reducer reads coalesced.
__global__ __launch_bounds__(256) void gemm3k(
    const bf16* __restrict__ A, const bf16* __restrict__ Wt,
    float* __restrict__ part, int K) {
  __shared__ __align__(16) bf16 As[64][32];
  __shared__ __align__(16) bf16 Bs[16][32];
  const int t = threadIdx.x;
  const int wv = t >> 6, lane = t & 63, quad = lane >> 4, lr = lane & 15;
  const int m0 = blockIdx.x * 64;
  const int kc = blockIdx.y;
  const int srow = t >> 2, scol = (t & 3) * 8;
  const bf16* gA = A + (size_t)(m0 + srow) * K + scol;
  const bf16* gB = Wt + (size_t)srow * K + scol;  // rows 0..15 for t<64
  void* ldsA = (char*)(&As[0][0]) + wv * 1024;
  f32x4_t acc = {0.f, 0.f, 0.f, 0.f};
  const int kbeg = kc * 448;
  for (int k0 = kbeg; k0 < kbeg + 448; k0 += 32) {
    gld_lds16(gA + k0, ldsA);
    if (wv == 0) gld_lds16(gB + k0, (void*)(&Bs[0][0]));
    __syncthreads();
    bf16x8_t a = *(const bf16x8_t*)(&As[wv * 16 + lr][quad * 8]);
    bf16x8_t b = *(const bf16x8_t*)(&Bs[lr][quad * 8]);
    acc = __builtin_amdgcn_mfma_f32_16x16x32_bf16(a, b, acc, 0, 0, 0);
    __syncthreads();
  }
#pragma unroll
  for (int r = 0; r < 4; ++r)
    part[(size_t)kc * 131072 + (size_t)lr * 8192 + (m0 + wv * 16 + quad * 4 + r)] = acc[r];
}

// Reduce split-K partials + bias, log_softmax over 10 classes.
__global__ __launch_bounds__(256) void lsm(const float* __restrict__ part,
                                           const float* __restrict__ b3,
                                           float* __restrict__ out) {
  const int row = blockIdx.x * 256 + threadIdx.x;
  float v[10];
#pragma unroll
  for (int o = 0; o < 10; ++o) {
    float s = b3[o];
#pragma unroll
    for (int kc = 0; kc < 8; ++kc) s += part[(size_t)kc * 131072 + (size_t)o * 8192 + row];
    v[o] = s;
  }
  float m = v[0];
#pragma unroll
  for (int o = 1; o < 10; ++o) m = fmaxf(m, v[o]);
  float se = 0.f;
#pragma unroll
  for (int o = 0; o < 10; ++o) se += expf(v[o] - m);
  const float l = m + logf(se);
#pragma unroll
  for (int o = 0; o < 10; ++o) out[(size_t)row * 10 + o] = v[o] - l;
}

extern "C" void kernel_launch(void* const* d_in, const int* in_sizes, int n_in,
                              void* d_out, int out_size, void* d_ws, size_t ws_size,
                              hipStream_t stream) {
  const float* x = (const float*)d_in[0];
  const float* coef1 = (const float*)d_in[1];
  const float* sb1 = (const float*)d_in[2];
  const float* sp1 = (const float*)d_in[3];
  const float* b1 = (const float*)d_in[4];
  const float* coef2 = (const float*)d_in[5];
  const float* sb2 = (const float*)d_in[6];
  const float* sp2 = (const float*)d_in[7];
  const float* b2 = (const float*)d_in[8];
  const float* coef3 = (const float*)d_in[9];
  const float* sb3 = (const float*)d_in[10];
  const float* sp3 = (const float*)d_in[11];
  const float* b3 = (const float*)d_in[12];
  float* out = (float*)d_out;

  char* ws = (char*)d_ws;
  size_t off = 0;
  bf16* A1 = (bf16*)(ws + off);  off += 11534336;   // 8192*704*2
  bf16* W1t = (bf16*)(ws + off); off += 360448;     // 256*704*2
  float* H1 = (float*)(ws + off); off += 8388608;   // 8192*256*4
  bf16* A2 = (bf16*)(ws + off);  off += 58720256;   // 8192*3584*2 (reused for A3)
  bf16* W2t = (bf16*)(ws + off); off += 1835008;    // 256*3584*2
  float* H2 = (float*)(ws + off); off += 8388608;
  bf16* W3t = (bf16*)(ws + off); off += 114688;     // 16*3584*2
  float* part = (float*)(ws + off); off += 4194304; // 8*16*8192*4

  prep_w<<<704, 256, 0, stream>>>(coef1, sb1, sp1, W1t, 49, 256, 256, 704);
  prep_w<<<3584, 256, 0, stream>>>(coef2, sb2, sp2, W2t, 256, 256, 256, 3584);
  prep_w<<<224, 256, 0, stream>>>(coef3, sb3, sp3, W3t, 256, 10, 16, 3584);

  pool_basis1<<<8192, 256, 0, stream>>>(x, A1);
  gemm64<<<dim3(128, 4), 256, 0, stream>>>(A1, W1t, b1, H1, 704);
  basis23<<<8192, 256, 0, stream>>>(H1, A2);
  gemm64<<<dim3(128, 4), 256, 0, stream>>>(A2, W2t, b2, H2, 3584);
  basis23<<<8192, 256, 0, stream>>>(H2, A2);
  gemm3k<<<dim3(128, 8), 256, 0, stream>>>(A2, W3t, part, 3584);
  lsm<<<32, 256, 0, stream>>>(part, b3, out);
}